// Round 12
// baseline (2023.479 us; speedup 1.0000x reference)
//
#include <hip/hip_runtime.h>
#include <stdint.h>

#define S_LEN 2048
#define D_DIM 128

typedef __attribute__((ext_vector_type(8)))  short bf16x8;
typedef __attribute__((ext_vector_type(4)))  short bf16x4;
typedef __attribute__((ext_vector_type(4)))  float f32x4;
typedef __attribute__((ext_vector_type(2)))  float f32x2;
typedef __attribute__((ext_vector_type(16))) float f32x16;

__device__ __forceinline__ short f2bf(float f) {
  union { float f; uint32_t u; } c; c.f = f;
  uint32_t u = c.u;
  u += 0x7fffu + ((u >> 16) & 1u);
  return (short)(u >> 16);
}
__device__ __forceinline__ uint32_t pk2bf(float a, float b) {
#if __has_builtin(__builtin_amdgcn_cvt_pk_bf16_f32)
  typedef __attribute__((ext_vector_type(2))) __bf16 bf2;
  union { bf2 v; uint32_t u; } cv;
  cv.v = __builtin_amdgcn_cvt_pk_bf16_f32(a, b);
  return cv.u;
#else
  return (uint32_t)(uint16_t)f2bf(a) | (((uint32_t)(uint16_t)f2bf(b)) << 16);
#endif
}
__device__ __forceinline__ float fexp2(float x) {
#if __has_builtin(__builtin_amdgcn_exp2f)
  return __builtin_amdgcn_exp2f(x);   // raw v_exp_f32, no ocml guard code
#else
  return exp2f(x);
#endif
}
__device__ __forceinline__ bf16x8 mk8(uint32_t a, uint32_t b, uint32_t c, uint32_t d) {
  union { uint32_t u[4]; bf16x8 v; } x;
  x.u[0] = a; x.u[1] = b; x.u[2] = c; x.u[3] = d;
  return x.v;
}
__device__ __forceinline__ void gl_lds16(const short* g, short* l) {
  __builtin_amdgcn_global_load_lds((const __attribute__((address_space(1))) void*)g,
                                   (__attribute__((address_space(3))) void*)l, 16, 0, 0);
}

// ---------------- preprocess ----------------
// blocks [0,512): V -> Vt bf16, transposed to [bh][d][key], keys bit-swapped
// (b2<->b3 per 16-group) to match attn_main's in-register P permutation.
// blocks [512,2560): K fp32->bf16 linear.
__global__ __launch_bounds__(256) void pre_kernel(
    const float* __restrict__ K, const float* __restrict__ V,
    short* __restrict__ Kb, short* __restrict__ Vt) {
  const int t = threadIdx.x;
  if (blockIdx.x >= 512) {
    int i0 = (blockIdx.x - 512) * 256 + t;
#pragma unroll
    for (int r = 0; r < 4; ++r) {
      int i = i0 + r * 524288;
      f32x4 v = ((const f32x4*)K)[i];
      *(uint2*)(Kb + (size_t)i * 4) = make_uint2(pk2bf(v[0], v[1]), pk2bf(v[2], v[3]));
    }
    return;
  }
  __shared__ __align__(16) uint32_t sU[128][64];  // [d][swizzled k2]
  const int vb = blockIdx.x;
  const int bh = vb >> 4;
  const int k0 = (vb & 15) * 128;
  const float* src = V + ((size_t)bh * S_LEN + k0) * D_DIM;
  {
    // phase 1: load key-row pairs coalesced, pack along k, conflict-free b32 writes
    const int a = t & 31;               // d4 = 4a
    const int E = 2 * (a & 15);
    const float* s0 = src + (size_t)(t >> 5) * 2 * D_DIM + a * 4;
#pragma unroll
    for (int p = 0; p < 8; ++p) {
      f32x4 vA = *(const f32x4*)(s0 + p * 16 * D_DIM);
      f32x4 vB = *(const f32x4*)(s0 + p * 16 * D_DIM + D_DIM);
      const int k2 = p * 8 + (t >> 5);  // u32 index = key pair (2k2, 2k2+1)
      const int col = k2 ^ E;
#pragma unroll
      for (int j = 0; j < 4; ++j)
        sU[4 * a + j][col] = pk2bf(vA[j], vB[j]);
    }
  }
  __syncthreads();
  {
    // phase 2: per thread one d-row; 8 x 16B stores; 2 x ds_read_b64 each.
    const int d = t >> 1;
    const int E = 2 * ((t >> 3) & 15);  // 2*((d>>2)&15)
    short* out = Vt + ((size_t)bh * D_DIM + d) * S_LEN + k0 + (t & 1) * 8;
#pragma unroll
    for (int g = 0; g < 8; ++g) {
      const int pb = g * 16 + (t & 1) * 8;
      const int kb1 = ((pb >> 4) << 4) + ((pb & 15) ? 4 : 0);  // bit2<->bit3 swap
      const int k2a = kb1 >> 1;         // even
      const int k2b = k2a + 4;          // kb2 = kb1 + 8
      uint2 lo = *(const uint2*)&sU[d][k2a ^ E];
      uint2 hi = *(const uint2*)&sU[d][k2b ^ E];
      uint4 o; o.x = lo.x; o.y = lo.y; o.z = hi.x; o.w = hi.y;
      *(uint4*)(out + g * 16) = o;
    }
  }
}

// ---------------- main kernel ----------------
// Round-7 champion structure with a register-NEUTRAL intra-chunk reorder:
// the OWN half of PV (4 MFMA; needs only this wave's pf + V(G), which is
// staged since barrier-1) moves BEFORE barrier-2, overlapping the tree-sum
// VALU and other waves' softmax skew. Barrier-2 is lgkm-only (proven in
// rounds 8/9): sP/sRed visibility needs lgkm only, so stage(G+1) stays in
// flight through PV. No setprio (round 9 suggests it was neutral-to-bad).
// Own/foreign V offsets and sP offsets pre-split into named arrays indexed
// by compile-time t2 only (rule #20: no runtime array subscripts).
__global__ __launch_bounds__(256, 2) void attn_main(
    const short* __restrict__ Kb, const short* __restrict__ Vt,
    const float* __restrict__ Q, float* __restrict__ O) {
  __shared__ __align__(16) short ring[2][16384];  // per slot: K 16KB | V 16KB
  __shared__ __align__(16) short sP[4096];        // 8 regions x 512 (qp,hw,t2)
  __shared__ float sRed[128];                     // [64 q][2 h]
  __shared__ float sLinv[64];
  // total LDS = 65536 + 8192 + 512 + 256 = 74496 B -> 2 blocks/CU

  const int t = threadIdx.x;
  const int w = t >> 6;
  const int lane = t & 63;
  const int l31 = lane & 31;
  const int hi = lane >> 5;
  const int h = w & 1;
  const int qp = w >> 1;

  // XCD swizzle: bh = (b&7)*4 + ((b>>3)&3), qtile = b>>5
  const int b = blockIdx.x;
  const int bh = (b & 7) * 4 + ((b >> 3) & 3);
  const int q0 = (b >> 5) * 64;

  const short* Kh = Kb + (size_t)bh * S_LEN * D_DIM;
  const short* Vh = Vt + (size_t)bh * D_DIM * S_LEN;

  // staging constants (K rows: 16 granules, mask 15; V rows: 8 granules, mask 7)
  const int kKey = t >> 4;                       // + r*16
  const int kG   = (t & 15) ^ (kKey & 15);
  const int vD   = t >> 3;                       // + r*32
  const int vG   = (t & 7) ^ (vD & 7);

  auto stageK = [&](int key0, int slot) {
    const short* src = Kh + (size_t)(key0 + kKey) * D_DIM + kG * 8;
    short* dst = &ring[slot][t * 8];
#pragma unroll
    for (int r = 0; r < 4; ++r) gl_lds16(src + r * 16 * D_DIM, dst + r * 2048);
  };
  auto stageV = [&](int key0, int slot) {
    const short* src = Vh + (size_t)vD * S_LEN + key0 + vG * 8;
    short* dst = &ring[slot][8192 + t * 8];
#pragma unroll
    for (int r = 0; r < 4; ++r) gl_lds16(src + (size_t)r * 32 * S_LEN, dst + r * 2048);
  };

  // ---- Q fragments: load fp32, scale, pack (register-resident) ----
  bf16x8 qf[8];
  {
    const float QSCALE = 0.12751743f;  // 128^-0.5 * log2(e)
    const float* Qg = Q + ((size_t)bh * S_LEN + q0 + qp * 32 + l31) * D_DIM;
#pragma unroll
    for (int ks = 0; ks < 8; ++ks) {
      f32x4 a = *(const f32x4*)(Qg + ks * 16 + hi * 8);
      f32x4 c = *(const f32x4*)(Qg + ks * 16 + hi * 8 + 4);
      qf[ks] = mk8(pk2bf(a[0] * QSCALE, a[1] * QSCALE), pk2bf(a[2] * QSCALE, a[3] * QSCALE),
                   pk2bf(c[0] * QSCALE, c[1] * QSCALE), pk2bf(c[2] * QSCALE, c[3] * QSCALE));
    }
  }

  // K A-frag LDS offsets (shorts): row = h*32+l31, logical granule 2ks+hi
  int aK[8];
#pragma unroll
  for (int ks = 0; ks < 8; ++ks)
    aK[ks] = (h * 32 + l31) * 128 + (((2 * ks + hi) ^ (l31 & 15)) << 3);
  // V B-frag offsets, pre-split own/foreign (row d = h*64 + l31; kstep
  // granule u = hw*2 + t2; XOR on l31&7). h enters values, never subscripts.
  int aVown[2], aVfor[2], spF[2];
#pragma unroll
  for (int t2 = 0; t2 < 2; ++t2) {
    const int uo = h * 2 + t2, uf = (1 - h) * 2 + t2;
    aVown[t2] = (h * 64 + l31) * 64 + (((uo * 2 + hi) ^ (l31 & 7)) << 3);
    aVfor[t2] = (h * 64 + l31) * 64 + (((uf * 2 + hi) ^ (l31 & 7)) << 3);
    spF[t2] = ((qp * 2 + (1 - h)) * 2 + t2) * 512 + lane * 8;
  }

  f32x16 oa[2], oj[2], ojb[2];
#pragma unroll
  for (int d = 0; d < 2; ++d)
#pragma unroll
    for (int r = 0; r < 16; ++r) { oa[d][r] = 0.f; oj[d][r] = 0.f; ojb[d][r] = 0.f; }

  float ssum = 0.f;
  const int spOwn = ((qp * 2 + h) * 2) * 512 + lane * 8;

  stageK(0, 0); stageV(0, 0);

  for (int j = 0; j < 8; ++j) {
#pragma unroll
    for (int c = 0; c < 4; ++c) {
      const int G = j * 4 + c;
      const int slot = G & 1;
      __syncthreads();  // chunk G staged (vmcnt drain = stage(G)); sP(G-1)
                        // consumed; ring[slot^1] free
      if (G + 1 < 32) { stageK((G + 1) * 64, slot ^ 1); stageV((G + 1) * 64, slot ^ 1); }

      if (c == 0 && j > 0) {
        // normalize previous block: oa += (oj + ojb) * linv (then clear)
        f32x4 lv[4];
#pragma unroll
        for (int g = 0; g < 4; ++g) lv[g] = *(const f32x4*)&sLinv[qp * 32 + g * 8 + hi * 4];
#pragma unroll
        for (int d = 0; d < 2; ++d)
#pragma unroll
          for (int r = 0; r < 16; ++r) {
            oa[d][r] += (oj[d][r] + ojb[d][r]) * lv[r >> 2][r & 3];
            oj[d][r] = 0.f;
            ojb[d][r] = 0.f;
          }
      }

      // ---- QK^T: one 32x32 tile, TWO independent MFMA chains (depth 4) ----
      const short* pK = &ring[slot][0];
      f32x16 sc0, sc1;
#pragma unroll
      for (int r = 0; r < 16; ++r) { sc0[r] = 0.f; sc1[r] = 0.f; }
#pragma unroll
      for (int ks = 0; ks < 4; ++ks) {
        bf16x8 a0 = *(const bf16x8*)(pK + aK[2 * ks]);
        bf16x8 a1 = *(const bf16x8*)(pK + aK[2 * ks + 1]);
        sc0 = __builtin_amdgcn_mfma_f32_32x32x16_bf16(a0, qf[2 * ks], sc0, 0, 0, 0);
        sc1 = __builtin_amdgcn_mfma_f32_32x32x16_bf16(a1, qf[2 * ks + 1], sc1, 0, 0, 0);
      }
      f32x16 sc;
#pragma unroll
      for (int r = 0; r < 16; ++r) sc[r] = fexp2(sc0[r] + sc1[r]);

      // pack unnormalized P to A-frags; write to sP
      bf16x8 pf[2];
#pragma unroll
      for (int t2 = 0; t2 < 2; ++t2) {
        pf[t2] = mk8(pk2bf(sc[8 * t2 + 0], sc[8 * t2 + 1]), pk2bf(sc[8 * t2 + 2], sc[8 * t2 + 3]),
                     pk2bf(sc[8 * t2 + 4], sc[8 * t2 + 5]), pk2bf(sc[8 * t2 + 6], sc[8 * t2 + 7]));
        *(bf16x8*)(sP + spOwn + t2 * 512) = pf[t2];
      }

      // ---- PV-own (PRE-barrier): own pf x own-key V granules.
      // V(G) staged since barrier-1; overlaps tree-sum + other waves' softmax.
      // Own keys go to oj if h==0 else ojb (key-half identity of oj/ojb kept).
      const short* pV = &ring[slot][8192];
#pragma unroll
      for (int t2 = 0; t2 < 2; ++t2) {
        bf16x8 a = pf[t2];
#pragma unroll
        for (int dt = 0; dt < 2; ++dt) {
          bf16x8 bv = *(const bf16x8*)(pV + aVown[t2] + dt * 2048);
          if (h == 0)
            oj[dt] = __builtin_amdgcn_mfma_f32_32x32x16_bf16(a, bv, oj[dt], 0, 0, 0);
          else
            ojb[dt] = __builtin_amdgcn_mfma_f32_32x32x16_bf16(a, bv, ojb[dt], 0, 0, 0);
        }
      }

      {  // tree-sum (depth 4)
        float a0 = sc[0] + sc[1], a1 = sc[2] + sc[3], a2 = sc[4] + sc[5], a3 = sc[6] + sc[7];
        float a4 = sc[8] + sc[9], a5 = sc[10] + sc[11], a6 = sc[12] + sc[13], a7 = sc[14] + sc[15];
        float b0 = a0 + a1, b1 = a2 + a3, b2 = a4 + a5, b3 = a6 + a7;
        ssum += (b0 + b1) + (b2 + b3);
      }
      if (c == 3) {
        ssum += __shfl_xor(ssum, 32);
        if (lane < 32) sRed[(qp * 32 + l31) * 2 + h] = ssum;
        ssum = 0.f;
      }

      // barrier-2: sP/sRed visibility needs lgkm only -- stage(G+1) stays in
      // flight (proven correct rounds 8/9).
      asm volatile("s_waitcnt lgkmcnt(0)\n\ts_barrier" ::: "memory");
      if (c == 3 && h == 0 && lane < 32) {
        f32x2 s2 = *(const f32x2*)&sRed[(qp * 32 + l31) * 2];
        sLinv[qp * 32 + l31] = __fdividef(1.0f, s2[0] + s2[1]);
      }

      // ---- PV-foreign (post-barrier): partner's P from sP x foreign-key V ----
#pragma unroll
      for (int t2 = 0; t2 < 2; ++t2) {
        bf16x8 a = *(const bf16x8*)(sP + spF[t2]);
#pragma unroll
        for (int dt = 0; dt < 2; ++dt) {
          bf16x8 bv = *(const bf16x8*)(pV + aVfor[t2] + dt * 2048);
          if (h == 0)
            ojb[dt] = __builtin_amdgcn_mfma_f32_32x32x16_bf16(a, bv, ojb[dt], 0, 0, 0);
          else
            oj[dt] = __builtin_amdgcn_mfma_f32_32x32x16_bf16(a, bv, oj[dt], 0, 0, 0);
        }
      }
    }
  }

  __syncthreads();
  // final normalize + store
  {
    f32x4 lv[4];
#pragma unroll
    for (int g = 0; g < 4; ++g) lv[g] = *(const f32x4*)&sLinv[qp * 32 + g * 8 + hi * 4];
    float* Og = O + ((size_t)bh * S_LEN + q0) * D_DIM;
#pragma unroll
    for (int d = 0; d < 2; ++d)
#pragma unroll
      for (int r = 0; r < 16; ++r) {
        float val = oa[d][r] + (oj[d][r] + ojb[d][r]) * lv[r >> 2][r & 3];
        int row = qp * 32 + (r & 3) + 8 * (r >> 2) + 4 * hi;
        int col = h * 64 + d * 32 + l31;
        Og[row * D_DIM + col] = val;
      }
  }
}

extern "C" void kernel_launch(void* const* d_in, const int* in_sizes, int n_in,
                              void* d_out, int out_size, void* d_ws, size_t ws_size,
                              hipStream_t stream) {
  const float* Q = (const float*)d_in[0];
  const float* K = (const float*)d_in[1];
  const float* V = (const float*)d_in[2];
  float* Out = (float*)d_out;
  const size_t tElems = (size_t)32 * S_LEN * D_DIM;

  short* Kb  = (short*)d_ws;
  short* Vtb = Kb + tElems;

  pre_kernel<<<2560, 256, 0, stream>>>(K, V, Kb, Vtb);
  attn_main<<<1024, 256, 0, stream>>>(Kb, Vtb, Q, Out);
}

// Round 13
// 221.935 us; speedup vs baseline: 9.1174x; 9.1174x over previous
//
#include <hip/hip_runtime.h>
#include <stdint.h>

#define S_LEN 2048
#define D_DIM 128

typedef __attribute__((ext_vector_type(8)))  short bf16x8;
typedef __attribute__((ext_vector_type(4)))  short bf16x4;
typedef __attribute__((ext_vector_type(4)))  float f32x4;
typedef __attribute__((ext_vector_type(2)))  float f32x2;
typedef __attribute__((ext_vector_type(16))) float f32x16;

__device__ __forceinline__ short f2bf(float f) {
  union { float f; uint32_t u; } c; c.f = f;
  uint32_t u = c.u;
  u += 0x7fffu + ((u >> 16) & 1u);
  return (short)(u >> 16);
}
__device__ __forceinline__ uint32_t pk2bf(float a, float b) {
#if __has_builtin(__builtin_amdgcn_cvt_pk_bf16_f32)
  typedef __attribute__((ext_vector_type(2))) __bf16 bf2;
  union { bf2 v; uint32_t u; } cv;
  cv.v = __builtin_amdgcn_cvt_pk_bf16_f32(a, b);
  return cv.u;
#else
  return (uint32_t)(uint16_t)f2bf(a) | (((uint32_t)(uint16_t)f2bf(b)) << 16);
#endif
}
__device__ __forceinline__ float fexp2(float x) {
#if __has_builtin(__builtin_amdgcn_exp2f)
  return __builtin_amdgcn_exp2f(x);   // raw v_exp_f32, no ocml guard code
#else
  return exp2f(x);
#endif
}
__device__ __forceinline__ bf16x8 mk8(uint32_t a, uint32_t b, uint32_t c, uint32_t d) {
  union { uint32_t u[4]; bf16x8 v; } x;
  x.u[0] = a; x.u[1] = b; x.u[2] = c; x.u[3] = d;
  return x.v;
}
__device__ __forceinline__ void gl_lds16(const short* g, short* l) {
  __builtin_amdgcn_global_load_lds((const __attribute__((address_space(1))) void*)g,
                                   (__attribute__((address_space(3))) void*)l, 16, 0, 0);
}

// ---------------- preprocess ----------------
// blocks [0,512): V -> Vt bf16, transposed to [bh][d][key], keys bit-swapped
// (b2<->b3 per 16-group) to match attn_main's in-register P permutation.
// blocks [512,2560): K fp32->bf16 linear.
__global__ __launch_bounds__(256) void pre_kernel(
    const float* __restrict__ K, const float* __restrict__ V,
    short* __restrict__ Kb, short* __restrict__ Vt) {
  const int t = threadIdx.x;
  if (blockIdx.x >= 512) {
    int i0 = (blockIdx.x - 512) * 256 + t;
#pragma unroll
    for (int r = 0; r < 4; ++r) {
      int i = i0 + r * 524288;
      f32x4 v = ((const f32x4*)K)[i];
      *(uint2*)(Kb + (size_t)i * 4) = make_uint2(pk2bf(v[0], v[1]), pk2bf(v[2], v[3]));
    }
    return;
  }
  __shared__ __align__(16) uint32_t sU[128][64];  // [d][swizzled k2]
  const int vb = blockIdx.x;
  const int bh = vb >> 4;
  const int k0 = (vb & 15) * 128;
  const float* src = V + ((size_t)bh * S_LEN + k0) * D_DIM;
  {
    // phase 1: load key-row pairs coalesced, pack along k, conflict-free b32 writes
    const int a = t & 31;               // d4 = 4a
    const int E = 2 * (a & 15);
    const float* s0 = src + (size_t)(t >> 5) * 2 * D_DIM + a * 4;
#pragma unroll
    for (int p = 0; p < 8; ++p) {
      f32x4 vA = *(const f32x4*)(s0 + p * 16 * D_DIM);
      f32x4 vB = *(const f32x4*)(s0 + p * 16 * D_DIM + D_DIM);
      const int k2 = p * 8 + (t >> 5);  // u32 index = key pair (2k2, 2k2+1)
      const int col = k2 ^ E;
#pragma unroll
      for (int j = 0; j < 4; ++j)
        sU[4 * a + j][col] = pk2bf(vA[j], vB[j]);
    }
  }
  __syncthreads();
  {
    // phase 2: per thread one d-row; 8 x 16B stores; 2 x ds_read_b64 each.
    const int d = t >> 1;
    const int E = 2 * ((t >> 3) & 15);  // 2*((d>>2)&15)
    short* out = Vt + ((size_t)bh * D_DIM + d) * S_LEN + k0 + (t & 1) * 8;
#pragma unroll
    for (int g = 0; g < 8; ++g) {
      const int pb = g * 16 + (t & 1) * 8;
      const int kb1 = ((pb >> 4) << 4) + ((pb & 15) ? 4 : 0);  // bit2<->bit3 swap
      const int k2a = kb1 >> 1;         // even
      const int k2b = k2a + 4;          // kb2 = kb1 + 8
      uint2 lo = *(const uint2*)&sU[d][k2a ^ E];
      uint2 hi = *(const uint2*)&sU[d][k2b ^ E];
      uint4 o; o.x = lo.x; o.y = lo.y; o.z = hi.x; o.w = hi.y;
      *(uint4*)(out + g * 16) = o;
    }
  }
}

// ---------------- main kernel ----------------
// Round-7 champion structure, restored verbatim (session best: 118.6 us).
// sP exchange, oa/oj/ojb split accumulators, split QK chains, raw exp2,
// V staged in LDS. Rounds 8-12 established:
//  - any variant adding >=16-32 live regs spills (256-reg wave budget at
//    2 waves/SIMD is saturated by this shape);
//  - MFMA accumulator destinations must be selected by COMPILE-TIME control
//    flow only (round 12: wave-uniform runtime branch -> predicated f32x16
//    copies -> 9.5 GB scratch traffic);
//  - lgkm-only barrier-2 and setprio are neutral (round 9).
__global__ __launch_bounds__(256, 2) void attn_main(
    const short* __restrict__ Kb, const short* __restrict__ Vt,
    const float* __restrict__ Q, float* __restrict__ O) {
  __shared__ __align__(16) short ring[2][16384];  // per slot: K 16KB | V 16KB
  __shared__ __align__(16) short sP[4096];        // 8 regions x 512 (qp,hw,t2)
  __shared__ float sRed[128];                     // [64 q][2 h]
  __shared__ float sLinv[64];
  // total LDS = 65536 + 8192 + 512 + 256 = 74496 B -> 2 blocks/CU

  const int t = threadIdx.x;
  const int w = t >> 6;
  const int lane = t & 63;
  const int l31 = lane & 31;
  const int hi = lane >> 5;
  const int h = w & 1;
  const int qp = w >> 1;

  // XCD swizzle: bh = (b&7)*4 + ((b>>3)&3), qtile = b>>5
  const int b = blockIdx.x;
  const int bh = (b & 7) * 4 + ((b >> 3) & 3);
  const int q0 = (b >> 5) * 64;

  const short* Kh = Kb + (size_t)bh * S_LEN * D_DIM;
  const short* Vh = Vt + (size_t)bh * D_DIM * S_LEN;

  // staging constants (K rows: 16 granules, mask 15; V rows: 8 granules, mask 7)
  const int kKey = t >> 4;                       // + r*16
  const int kG   = (t & 15) ^ (kKey & 15);
  const int vD   = t >> 3;                       // + r*32
  const int vG   = (t & 7) ^ (vD & 7);

  auto stageK = [&](int key0, int slot) {
    const short* src = Kh + (size_t)(key0 + kKey) * D_DIM + kG * 8;
    short* dst = &ring[slot][t * 8];
#pragma unroll
    for (int r = 0; r < 4; ++r) gl_lds16(src + r * 16 * D_DIM, dst + r * 2048);
  };
  auto stageV = [&](int key0, int slot) {
    const short* src = Vh + (size_t)vD * S_LEN + key0 + vG * 8;
    short* dst = &ring[slot][8192 + t * 8];
#pragma unroll
    for (int r = 0; r < 4; ++r) gl_lds16(src + (size_t)r * 32 * S_LEN, dst + r * 2048);
  };

  // ---- Q fragments: load fp32, scale, pack (register-resident) ----
  bf16x8 qf[8];
  {
    const float QSCALE = 0.12751743f;  // 128^-0.5 * log2(e)
    const float* Qg = Q + ((size_t)bh * S_LEN + q0 + qp * 32 + l31) * D_DIM;
#pragma unroll
    for (int ks = 0; ks < 8; ++ks) {
      f32x4 a = *(const f32x4*)(Qg + ks * 16 + hi * 8);
      f32x4 c = *(const f32x4*)(Qg + ks * 16 + hi * 8 + 4);
      qf[ks] = mk8(pk2bf(a[0] * QSCALE, a[1] * QSCALE), pk2bf(a[2] * QSCALE, a[3] * QSCALE),
                   pk2bf(c[0] * QSCALE, c[1] * QSCALE), pk2bf(c[2] * QSCALE, c[3] * QSCALE));
    }
  }

  // K A-frag LDS offsets (shorts): row = h*32+l31, logical granule 2ks+hi
  int aK[8];
#pragma unroll
  for (int ks = 0; ks < 8; ++ks)
    aK[ks] = (h * 32 + l31) * 128 + (((2 * ks + hi) ^ (l31 & 15)) << 3);
  // V B-frag LDS offsets: row d = h*64 (+dt*32) + l31, logical granule u*2+hi
  int aV[4];
#pragma unroll
  for (int u = 0; u < 4; ++u)
    aV[u] = (h * 64 + l31) * 64 + (((u * 2 + hi) ^ (l31 & 7)) << 3);

  f32x16 oa[2], oj[2], ojb[2];
#pragma unroll
  for (int d = 0; d < 2; ++d)
#pragma unroll
    for (int r = 0; r < 16; ++r) { oa[d][r] = 0.f; oj[d][r] = 0.f; ojb[d][r] = 0.f; }

  float ssum = 0.f;
  const int spOwn = ((qp * 2 + h) * 2) * 512 + lane * 8;

  stageK(0, 0); stageV(0, 0);

  for (int j = 0; j < 8; ++j) {
#pragma unroll
    for (int c = 0; c < 4; ++c) {
      const int G = j * 4 + c;
      const int slot = G & 1;
      __syncthreads();  // chunk G staged; sP(G-1) consumed; ring[slot^1] free
      if (G + 1 < 32) { stageK((G + 1) * 64, slot ^ 1); stageV((G + 1) * 64, slot ^ 1); }

      if (c == 0 && j > 0) {
        // normalize previous block: oa += (oj + ojb) * linv (then clear)
        f32x4 lv[4];
#pragma unroll
        for (int g = 0; g < 4; ++g) lv[g] = *(const f32x4*)&sLinv[qp * 32 + g * 8 + hi * 4];
#pragma unroll
        for (int d = 0; d < 2; ++d)
#pragma unroll
          for (int r = 0; r < 16; ++r) {
            oa[d][r] += (oj[d][r] + ojb[d][r]) * lv[r >> 2][r & 3];
            oj[d][r] = 0.f;
            ojb[d][r] = 0.f;
          }
      }

      // ---- QK^T: one 32x32 tile, TWO independent MFMA chains (depth 4) ----
      const short* pK = &ring[slot][0];
      f32x16 sc0, sc1;
#pragma unroll
      for (int r = 0; r < 16; ++r) { sc0[r] = 0.f; sc1[r] = 0.f; }
#pragma unroll
      for (int ks = 0; ks < 4; ++ks) {
        bf16x8 a0 = *(const bf16x8*)(pK + aK[2 * ks]);
        bf16x8 a1 = *(const bf16x8*)(pK + aK[2 * ks + 1]);
        sc0 = __builtin_amdgcn_mfma_f32_32x32x16_bf16(a0, qf[2 * ks], sc0, 0, 0, 0);
        sc1 = __builtin_amdgcn_mfma_f32_32x32x16_bf16(a1, qf[2 * ks + 1], sc1, 0, 0, 0);
      }
      f32x16 sc;
#pragma unroll
      for (int r = 0; r < 16; ++r) sc[r] = fexp2(sc0[r] + sc1[r]);

      // pack unnormalized P to A-frags; write to sP ASAP (barrier-bound path)
      bf16x8 pf[2];
#pragma unroll
      for (int t2 = 0; t2 < 2; ++t2) {
        pf[t2] = mk8(pk2bf(sc[8 * t2 + 0], sc[8 * t2 + 1]), pk2bf(sc[8 * t2 + 2], sc[8 * t2 + 3]),
                     pk2bf(sc[8 * t2 + 4], sc[8 * t2 + 5]), pk2bf(sc[8 * t2 + 6], sc[8 * t2 + 7]));
        *(bf16x8*)(sP + spOwn + t2 * 512) = pf[t2];
      }
      {  // tree-sum (depth 4)
        float a0 = sc[0] + sc[1], a1 = sc[2] + sc[3], a2 = sc[4] + sc[5], a3 = sc[6] + sc[7];
        float a4 = sc[8] + sc[9], a5 = sc[10] + sc[11], a6 = sc[12] + sc[13], a7 = sc[14] + sc[15];
        float b0 = a0 + a1, b1 = a2 + a3, b2 = a4 + a5, b3 = a6 + a7;
        ssum += (b0 + b1) + (b2 + b3);
      }
      if (c == 3) {
        ssum += __shfl_xor(ssum, 32);
        if (lane < 32) sRed[(qp * 32 + l31) * 2 + h] = ssum;
        ssum = 0.f;
      }
      __syncthreads();  // sP ready (+ sRed at c==3)
      if (c == 3 && h == 0 && lane < 32) {
        f32x2 s2 = *(const f32x2*)&sRed[(qp * 32 + l31) * 2];
        sLinv[qp * 32 + l31] = __fdividef(1.0f, s2[0] + s2[1]);
      }

      // ---- PV: 4 (hw,t2) ksteps x 2 d-tiles; hw=0 -> oj, hw=1 -> ojb ----
      const short* pV = &ring[slot][8192];
#pragma unroll
      for (int hw = 0; hw < 2; ++hw)
#pragma unroll
        for (int t2 = 0; t2 < 2; ++t2) {
          bf16x8 a = (hw == h) ? pf[t2]
                               : *(const bf16x8*)(sP + ((qp * 2 + hw) * 2 + t2) * 512 + lane * 8);
#pragma unroll
          for (int dt = 0; dt < 2; ++dt) {
            bf16x8 bv = *(const bf16x8*)(pV + aV[hw * 2 + t2] + dt * 2048);
            if (hw == 0)
              oj[dt] = __builtin_amdgcn_mfma_f32_32x32x16_bf16(a, bv, oj[dt], 0, 0, 0);
            else
              ojb[dt] = __builtin_amdgcn_mfma_f32_32x32x16_bf16(a, bv, ojb[dt], 0, 0, 0);
          }
        }
    }
  }

  __syncthreads();
  // final normalize + store
  {
    f32x4 lv[4];
#pragma unroll
    for (int g = 0; g < 4; ++g) lv[g] = *(const f32x4*)&sLinv[qp * 32 + g * 8 + hi * 4];
    float* Og = O + ((size_t)bh * S_LEN + q0) * D_DIM;
#pragma unroll
    for (int d = 0; d < 2; ++d)
#pragma unroll
      for (int r = 0; r < 16; ++r) {
        float val = oa[d][r] + (oj[d][r] + ojb[d][r]) * lv[r >> 2][r & 3];
        int row = qp * 32 + (r & 3) + 8 * (r >> 2) + 4 * hi;
        int col = h * 64 + d * 32 + l31;
        Og[row * D_DIM + col] = val;
      }
  }
}

extern "C" void kernel_launch(void* const* d_in, const int* in_sizes, int n_in,
                              void* d_out, int out_size, void* d_ws, size_t ws_size,
                              hipStream_t stream) {
  const float* Q = (const float*)d_in[0];
  const float* K = (const float*)d_in[1];
  const float* V = (const float*)d_in[2];
  float* Out = (float*)d_out;
  const size_t tElems = (size_t)32 * S_LEN * D_DIM;

  short* Kb  = (short*)d_ws;
  short* Vtb = Kb + tElems;

  pre_kernel<<<2560, 256, 0, stream>>>(K, V, Kb, Vtb);
  attn_main<<<1024, 256, 0, stream>>>(Kb, Vtb, Q, Out);
}

// Round 14
// 221.512 us; speedup vs baseline: 9.1349x; 1.0019x over previous
//
#include <hip/hip_runtime.h>
#include <stdint.h>

#define S_LEN 2048
#define D_DIM 128

typedef __attribute__((ext_vector_type(8)))  short bf16x8;
typedef __attribute__((ext_vector_type(4)))  short bf16x4;
typedef __attribute__((ext_vector_type(4)))  float f32x4;
typedef __attribute__((ext_vector_type(2)))  float f32x2;
typedef __attribute__((ext_vector_type(16))) float f32x16;

__device__ __forceinline__ short f2bf(float f) {
  union { float f; uint32_t u; } c; c.f = f;
  uint32_t u = c.u;
  u += 0x7fffu + ((u >> 16) & 1u);
  return (short)(u >> 16);
}
__device__ __forceinline__ uint32_t pk2bf(float a, float b) {
#if __has_builtin(__builtin_amdgcn_cvt_pk_bf16_f32)
  typedef __attribute__((ext_vector_type(2))) __bf16 bf2;
  union { bf2 v; uint32_t u; } cv;
  cv.v = __builtin_amdgcn_cvt_pk_bf16_f32(a, b);
  return cv.u;
#else
  return (uint32_t)(uint16_t)f2bf(a) | (((uint32_t)(uint16_t)f2bf(b)) << 16);
#endif
}
__device__ __forceinline__ float fexp2(float x) {
#if __has_builtin(__builtin_amdgcn_exp2f)
  return __builtin_amdgcn_exp2f(x);   // raw v_exp_f32, no ocml guard code
#else
  return exp2f(x);
#endif
}
__device__ __forceinline__ bf16x8 mk8(uint32_t a, uint32_t b, uint32_t c, uint32_t d) {
  union { uint32_t u[4]; bf16x8 v; } x;
  x.u[0] = a; x.u[1] = b; x.u[2] = c; x.u[3] = d;
  return x.v;
}
__device__ __forceinline__ void gl_lds16(const short* g, short* l) {
  __builtin_amdgcn_global_load_lds((const __attribute__((address_space(1))) void*)g,
                                   (__attribute__((address_space(3))) void*)l, 16, 0, 0);
}

// ---------------- preprocess ----------------
// blocks [0,512): V -> Vt bf16, transposed to [bh][d][key], keys bit-swapped
// (b2<->b3 per 16-group) to match attn_main's in-register P permutation.
// blocks [512,2560): K fp32->bf16 linear.
__global__ __launch_bounds__(256) void pre_kernel(
    const float* __restrict__ K, const float* __restrict__ V,
    short* __restrict__ Kb, short* __restrict__ Vt) {
  const int t = threadIdx.x;
  if (blockIdx.x >= 512) {
    int i0 = (blockIdx.x - 512) * 256 + t;
#pragma unroll
    for (int r = 0; r < 4; ++r) {
      int i = i0 + r * 524288;
      f32x4 v = ((const f32x4*)K)[i];
      *(uint2*)(Kb + (size_t)i * 4) = make_uint2(pk2bf(v[0], v[1]), pk2bf(v[2], v[3]));
    }
    return;
  }
  __shared__ __align__(16) uint32_t sU[128][64];  // [d][swizzled k2]
  const int vb = blockIdx.x;
  const int bh = vb >> 4;
  const int k0 = (vb & 15) * 128;
  const float* src = V + ((size_t)bh * S_LEN + k0) * D_DIM;
  {
    // phase 1: load key-row pairs coalesced, pack along k, conflict-free b32 writes
    const int a = t & 31;               // d4 = 4a
    const int E = 2 * (a & 15);
    const float* s0 = src + (size_t)(t >> 5) * 2 * D_DIM + a * 4;
#pragma unroll
    for (int p = 0; p < 8; ++p) {
      f32x4 vA = *(const f32x4*)(s0 + p * 16 * D_DIM);
      f32x4 vB = *(const f32x4*)(s0 + p * 16 * D_DIM + D_DIM);
      const int k2 = p * 8 + (t >> 5);  // u32 index = key pair (2k2, 2k2+1)
      const int col = k2 ^ E;
#pragma unroll
      for (int j = 0; j < 4; ++j)
        sU[4 * a + j][col] = pk2bf(vA[j], vB[j]);
    }
  }
  __syncthreads();
  {
    // phase 2: per thread one d-row; 8 x 16B stores; 2 x ds_read_b64 each.
    const int d = t >> 1;
    const int E = 2 * ((t >> 3) & 15);  // 2*((d>>2)&15)
    short* out = Vt + ((size_t)bh * D_DIM + d) * S_LEN + k0 + (t & 1) * 8;
#pragma unroll
    for (int g = 0; g < 8; ++g) {
      const int pb = g * 16 + (t & 1) * 8;
      const int kb1 = ((pb >> 4) << 4) + ((pb & 15) ? 4 : 0);  // bit2<->bit3 swap
      const int k2a = kb1 >> 1;         // even
      const int k2b = k2a + 4;          // kb2 = kb1 + 8
      uint2 lo = *(const uint2*)&sU[d][k2a ^ E];
      uint2 hi = *(const uint2*)&sU[d][k2b ^ E];
      uint4 o; o.x = lo.x; o.y = lo.y; o.z = hi.x; o.w = hi.y;
      *(uint4*)(out + g * 16) = o;
    }
  }
}

// ---------------- main kernel ----------------
// Round-7/13 champion structure with the PV reorder done RIGHT:
//  - oj/ojb are symmetric summands (only ever used as oj+ojb), so their
//    roles are redefined: oj <- OWN-half PV contributions, ojb <- FOREIGN-
//    half PV contributions. Both accumulator choices are compile-time code
//    positions -- no runtime guard (round 12's 9.5 GB scratch bug), no new
//    register state (rounds 8/10/11's spill failure mode).
//  - PV-own (4 MFMA: own pf x V(G), resident since barrier-1) issues BEFORE
//    barrier-2, overlapping the tree-sum VALU and other waves' softmax skew.
//  - barrier-2 is lgkm-only (proven rounds 8/9): stage(G+1) stays in flight.
__global__ __launch_bounds__(256, 2) void attn_main(
    const short* __restrict__ Kb, const short* __restrict__ Vt,
    const float* __restrict__ Q, float* __restrict__ O) {
  __shared__ __align__(16) short ring[2][16384];  // per slot: K 16KB | V 16KB
  __shared__ __align__(16) short sP[4096];        // 8 regions x 512 (qp,hw,t2)
  __shared__ float sRed[128];                     // [64 q][2 h]
  __shared__ float sLinv[64];
  // total LDS = 65536 + 8192 + 512 + 256 = 74496 B -> 2 blocks/CU

  const int t = threadIdx.x;
  const int w = t >> 6;
  const int lane = t & 63;
  const int l31 = lane & 31;
  const int hi = lane >> 5;
  const int h = w & 1;
  const int qp = w >> 1;

  // XCD swizzle: bh = (b&7)*4 + ((b>>3)&3), qtile = b>>5
  const int b = blockIdx.x;
  const int bh = (b & 7) * 4 + ((b >> 3) & 3);
  const int q0 = (b >> 5) * 64;

  const short* Kh = Kb + (size_t)bh * S_LEN * D_DIM;
  const short* Vh = Vt + (size_t)bh * D_DIM * S_LEN;

  // staging constants (K rows: 16 granules, mask 15; V rows: 8 granules, mask 7)
  const int kKey = t >> 4;                       // + r*16
  const int kG   = (t & 15) ^ (kKey & 15);
  const int vD   = t >> 3;                       // + r*32
  const int vG   = (t & 7) ^ (vD & 7);

  auto stageK = [&](int key0, int slot) {
    const short* src = Kh + (size_t)(key0 + kKey) * D_DIM + kG * 8;
    short* dst = &ring[slot][t * 8];
#pragma unroll
    for (int r = 0; r < 4; ++r) gl_lds16(src + r * 16 * D_DIM, dst + r * 2048);
  };
  auto stageV = [&](int key0, int slot) {
    const short* src = Vh + (size_t)vD * S_LEN + key0 + vG * 8;
    short* dst = &ring[slot][8192 + t * 8];
#pragma unroll
    for (int r = 0; r < 4; ++r) gl_lds16(src + (size_t)r * 32 * S_LEN, dst + r * 2048);
  };

  // ---- Q fragments: load fp32, scale, pack (register-resident) ----
  bf16x8 qf[8];
  {
    const float QSCALE = 0.12751743f;  // 128^-0.5 * log2(e)
    const float* Qg = Q + ((size_t)bh * S_LEN + q0 + qp * 32 + l31) * D_DIM;
#pragma unroll
    for (int ks = 0; ks < 8; ++ks) {
      f32x4 a = *(const f32x4*)(Qg + ks * 16 + hi * 8);
      f32x4 c = *(const f32x4*)(Qg + ks * 16 + hi * 8 + 4);
      qf[ks] = mk8(pk2bf(a[0] * QSCALE, a[1] * QSCALE), pk2bf(a[2] * QSCALE, a[3] * QSCALE),
                   pk2bf(c[0] * QSCALE, c[1] * QSCALE), pk2bf(c[2] * QSCALE, c[3] * QSCALE));
    }
  }

  // K A-frag LDS offsets (shorts): row = h*32+l31, logical granule 2ks+hi
  int aK[8];
#pragma unroll
  for (int ks = 0; ks < 8; ++ks)
    aK[ks] = (h * 32 + l31) * 128 + (((2 * ks + hi) ^ (l31 & 15)) << 3);
  // V B-frag offsets pre-split own/foreign (d-row = h*64 + l31 (+dt*2048);
  // key-granule u = hw*2+t2 with hw = h (own) / 1-h (foreign); XOR on l31&7).
  // h enters VALUES only, never an array subscript (rule #20).
  int aVown[2], aVfor[2], spF[2];
#pragma unroll
  for (int t2 = 0; t2 < 2; ++t2) {
    const int uo = h * 2 + t2, uf = (1 - h) * 2 + t2;
    aVown[t2] = (h * 64 + l31) * 64 + (((uo * 2 + hi) ^ (l31 & 7)) << 3);
    aVfor[t2] = (h * 64 + l31) * 64 + (((uf * 2 + hi) ^ (l31 & 7)) << 3);
    spF[t2]   = ((qp * 2 + (1 - h)) * 2 + t2) * 512 + lane * 8;
  }

  f32x16 oa[2], oj[2], ojb[2];
#pragma unroll
  for (int d = 0; d < 2; ++d)
#pragma unroll
    for (int r = 0; r < 16; ++r) { oa[d][r] = 0.f; oj[d][r] = 0.f; ojb[d][r] = 0.f; }

  float ssum = 0.f;
  const int spOwn = ((qp * 2 + h) * 2) * 512 + lane * 8;

  stageK(0, 0); stageV(0, 0);

  for (int j = 0; j < 8; ++j) {
#pragma unroll
    for (int c = 0; c < 4; ++c) {
      const int G = j * 4 + c;
      const int slot = G & 1;
      __syncthreads();  // chunk G staged; sP(G-1) consumed; ring[slot^1] free
      if (G + 1 < 32) { stageK((G + 1) * 64, slot ^ 1); stageV((G + 1) * 64, slot ^ 1); }

      if (c == 0 && j > 0) {
        // normalize previous block: oa += (oj + ojb) * linv (then clear)
        f32x4 lv[4];
#pragma unroll
        for (int g = 0; g < 4; ++g) lv[g] = *(const f32x4*)&sLinv[qp * 32 + g * 8 + hi * 4];
#pragma unroll
        for (int d = 0; d < 2; ++d)
#pragma unroll
          for (int r = 0; r < 16; ++r) {
            oa[d][r] += (oj[d][r] + ojb[d][r]) * lv[r >> 2][r & 3];
            oj[d][r] = 0.f;
            ojb[d][r] = 0.f;
          }
      }

      // ---- QK^T: one 32x32 tile, TWO independent MFMA chains (depth 4) ----
      const short* pK = &ring[slot][0];
      f32x16 sc0, sc1;
#pragma unroll
      for (int r = 0; r < 16; ++r) { sc0[r] = 0.f; sc1[r] = 0.f; }
#pragma unroll
      for (int ks = 0; ks < 4; ++ks) {
        bf16x8 a0 = *(const bf16x8*)(pK + aK[2 * ks]);
        bf16x8 a1 = *(const bf16x8*)(pK + aK[2 * ks + 1]);
        sc0 = __builtin_amdgcn_mfma_f32_32x32x16_bf16(a0, qf[2 * ks], sc0, 0, 0, 0);
        sc1 = __builtin_amdgcn_mfma_f32_32x32x16_bf16(a1, qf[2 * ks + 1], sc1, 0, 0, 0);
      }
      f32x16 sc;
#pragma unroll
      for (int r = 0; r < 16; ++r) sc[r] = fexp2(sc0[r] + sc1[r]);

      // pack unnormalized P to A-frags; write to sP
      bf16x8 pf[2];
#pragma unroll
      for (int t2 = 0; t2 < 2; ++t2) {
        pf[t2] = mk8(pk2bf(sc[8 * t2 + 0], sc[8 * t2 + 1]), pk2bf(sc[8 * t2 + 2], sc[8 * t2 + 3]),
                     pk2bf(sc[8 * t2 + 4], sc[8 * t2 + 5]), pk2bf(sc[8 * t2 + 6], sc[8 * t2 + 7]));
        *(bf16x8*)(sP + spOwn + t2 * 512) = pf[t2];
      }

      // ---- PV-own (PRE-barrier): own pf x own-key V -> ALWAYS oj ----
      // V(G) resident since barrier-1; overlaps tree-sum + other waves'
      // softmax skew. Accumulator chosen by code position (compile-time).
      const short* pV = &ring[slot][8192];
#pragma unroll
      for (int t2 = 0; t2 < 2; ++t2) {
#pragma unroll
        for (int dt = 0; dt < 2; ++dt) {
          bf16x8 bv = *(const bf16x8*)(pV + aVown[t2] + dt * 2048);
          oj[dt] = __builtin_amdgcn_mfma_f32_32x32x16_bf16(pf[t2], bv, oj[dt], 0, 0, 0);
        }
      }

      {  // tree-sum (depth 4)
        float a0 = sc[0] + sc[1], a1 = sc[2] + sc[3], a2 = sc[4] + sc[5], a3 = sc[6] + sc[7];
        float a4 = sc[8] + sc[9], a5 = sc[10] + sc[11], a6 = sc[12] + sc[13], a7 = sc[14] + sc[15];
        float b0 = a0 + a1, b1 = a2 + a3, b2 = a4 + a5, b3 = a6 + a7;
        ssum += (b0 + b1) + (b2 + b3);
      }
      if (c == 3) {
        ssum += __shfl_xor(ssum, 32);
        if (lane < 32) sRed[(qp * 32 + l31) * 2 + h] = ssum;
        ssum = 0.f;
      }

      // barrier-2: sP/sRed visibility needs lgkm only -- stage(G+1) stays in
      // flight (correctness proven rounds 8/9).
      asm volatile("s_waitcnt lgkmcnt(0)\n\ts_barrier" ::: "memory");
      if (c == 3 && h == 0 && lane < 32) {
        f32x2 s2 = *(const f32x2*)&sRed[(qp * 32 + l31) * 2];
        sLinv[qp * 32 + l31] = __fdividef(1.0f, s2[0] + s2[1]);
      }

      // ---- PV-foreign (post-barrier): partner P x foreign-key V -> ALWAYS ojb ----
#pragma unroll
      for (int t2 = 0; t2 < 2; ++t2) {
        bf16x8 a = *(const bf16x8*)(sP + spF[t2]);
#pragma unroll
        for (int dt = 0; dt < 2; ++dt) {
          bf16x8 bv = *(const bf16x8*)(pV + aVfor[t2] + dt * 2048);
          ojb[dt] = __builtin_amdgcn_mfma_f32_32x32x16_bf16(a, bv, ojb[dt], 0, 0, 0);
        }
      }
    }
  }

  __syncthreads();
  // final normalize + store
  {
    f32x4 lv[4];
#pragma unroll
    for (int g = 0; g < 4; ++g) lv[g] = *(const f32x4*)&sLinv[qp * 32 + g * 8 + hi * 4];
    float* Og = O + ((size_t)bh * S_LEN + q0) * D_DIM;
#pragma unroll
    for (int d = 0; d < 2; ++d)
#pragma unroll
      for (int r = 0; r < 16; ++r) {
        float val = oa[d][r] + (oj[d][r] + ojb[d][r]) * lv[r >> 2][r & 3];
        int row = qp * 32 + (r & 3) + 8 * (r >> 2) + 4 * hi;
        int col = h * 64 + d * 32 + l31;
        Og[row * D_DIM + col] = val;
      }
  }
}

extern "C" void kernel_launch(void* const* d_in, const int* in_sizes, int n_in,
                              void* d_out, int out_size, void* d_ws, size_t ws_size,
                              hipStream_t stream) {
  const float* Q = (const float*)d_in[0];
  const float* K = (const float*)d_in[1];
  const float* V = (const float*)d_in[2];
  float* Out = (float*)d_out;
  const size_t tElems = (size_t)32 * S_LEN * D_DIM;

  short* Kb  = (short*)d_ws;
  short* Vtb = Kb + tElems;

  pre_kernel<<<2560, 256, 0, stream>>>(K, V, Kb, Vtb);
  attn_main<<<1024, 256, 0, stream>>>(Kb, Vtb, Q, Out);
}